// Round 1
// 393.245 us; speedup vs baseline: 2.0998x; 2.0998x over previous
//
#include <hip/hip_runtime.h>
#include <hip/hip_bf16.h>

// GroupLinearEncoder: N=64, L0=257,C0=1024, L1=197,C1=768, H=1024, P=2048, G=8, K=39548
// v2 pipeline:
//   pre-pass: x0,x1,w2_0,w2_1 -> bf16 copies in ws
//   gemm_fused<L>: m97-structure bf16 GEMM (global_load_lds w=16, BK=64, XOR-swizzled LDS)
//     with fused reduce epilogue: z[n,k] += sum_l M[n*L+l,k]*w1[k,l] via atomics (no Mbuf)
//   bn_latent, s_combine unchanged
//   gemm_embed: K-split x4 (grid 309x4) partials; reduce_out sums + 2*embed_b
// Workspace: x0b 16512*1024 + x1b 12672*768 + w2b 1024*(1024+768) bf16
//            + z0,z1,latT (3*64K f32) + s (128K f32); partials (4*64*39548 f32) alias bf16 region
//            total ~55.6 MiB

typedef __attribute__((ext_vector_type(4))) float f32x4;
typedef __attribute__((ext_vector_type(8))) short bf16x8;

__device__ __forceinline__ short f2bf(float v) {
  __hip_bfloat16 h = __float2bfloat16(v);
  union { __hip_bfloat16 b; short s; } u; u.b = h; return u.s;
}

__device__ __forceinline__ void gload16(const short* g, short* l) {
  __builtin_amdgcn_global_load_lds(
      (const __attribute__((address_space(1))) void*)g,
      (__attribute__((address_space(3))) void*)l, 16, 0, 0);
}

// f32 -> bf16, 8 elems/thread
__global__ __launch_bounds__(256) void to_bf16(const float* __restrict__ in,
                                               short* __restrict__ out, int n8)
{
  int i = blockIdx.x * 256 + threadIdx.x;
  if (i >= n8) return;
  const float4* p = reinterpret_cast<const float4*>(in) + 2 * (size_t)i;
  float4 a = p[0], b = p[1];
  bf16x8 o;
  o[0] = f2bf(a.x); o[1] = f2bf(a.y); o[2] = f2bf(a.z); o[3] = f2bf(a.w);
  o[4] = f2bf(b.x); o[5] = f2bf(b.y); o[6] = f2bf(b.z); o[7] = f2bf(b.w);
  *reinterpret_cast<bf16x8*>(out + 8 * (size_t)i) = o;
}

// C = A(bf16, Mpad x K) @ B(bf16, 1024 x K)^T, fused with
// z[n,col] += sum_l C[n*L+l, col] * w1[col*L + l]   (atomics; z pre-zeroed)
// 128x128 tile, BK=64, 4 waves (2x2), FM=FN=4.
// LDS linear [128][64] bf16 for global_load_lds; XOR swizzle applied on the
// GLOBAL source 16B-chunk index and again on ds_read (both-sides rule).
template<int L>
__global__ __launch_bounds__(256) void gemm_fused(
    const short* __restrict__ Ab, const short* __restrict__ Bb,
    const float* __restrict__ w1, float* __restrict__ z,
    int M, int K)
{
  __shared__ short As[128 * 64];
  __shared__ short Bs[128 * 64];
  const int tid  = threadIdx.x;
  const int lane = tid & 63;
  const int wave = tid >> 6;
  const int wm = wave >> 1, wn = wave & 1;     // 2x2 wave grid, 64x64 per wave
  const int tile_m = blockIdx.y * 128;
  const int tile_n = blockIdx.x * 128;         // < 1024 always
  const int rl = lane & 15;
  const int lh = lane >> 4;                    // 0..3

  f32x4 acc[4][4] = {};

  for (int k0 = 0; k0 < K; k0 += 64) {
    __syncthreads();
    // stage A: 128 rows x 64 bf16 = 16KB; 4x 16B chunks per thread.
    // chunk (r,cc) in LDS receives global chunk (r, cc^(r&7))  [involution]
#pragma unroll
    for (int c = 0; c < 4; ++c) {
      int o = (c * 256 + tid) * 16;            // byte offset in LDS (linear dest)
      int r = o >> 7;
      int sc = ((o >> 4) & 7) ^ (r & 7);
      gload16(Ab + (size_t)(tile_m + r) * K + k0 + sc * 8,
              (short*)((char*)As + o));
    }
#pragma unroll
    for (int c = 0; c < 4; ++c) {
      int o = (c * 256 + tid) * 16;
      int r = o >> 7;
      int sc = ((o >> 4) & 7) ^ (r & 7);
      gload16(Bb + (size_t)(tile_n + r) * K + k0 + sc * 8,
              (short*)((char*)Bs + o));
    }
    __syncthreads();  // compiler emits vmcnt(0) drain here

#pragma unroll
    for (int ks = 0; ks < 2; ++ks) {
      bf16x8 af[4], bfr[4];
#pragma unroll
      for (int mi = 0; mi < 4; ++mi) {
        int r = wm * 64 + mi * 16 + rl;
        int j = (ks * 4 + lh) ^ (r & 7);       // swizzled read
        af[mi] = *reinterpret_cast<const bf16x8*>((const char*)As + r * 128 + j * 16);
      }
#pragma unroll
      for (int ni = 0; ni < 4; ++ni) {
        int r = wn * 64 + ni * 16 + rl;
        int j = (ks * 4 + lh) ^ (r & 7);
        bfr[ni] = *reinterpret_cast<const bf16x8*>((const char*)Bs + r * 128 + j * 16);
      }
#pragma unroll
      for (int mi = 0; mi < 4; ++mi)
#pragma unroll
        for (int ni = 0; ni < 4; ++ni)
          acc[mi][ni] = __builtin_amdgcn_mfma_f32_16x16x32_bf16(af[mi], bfr[ni], acc[mi][ni], 0, 0, 0);
    }
  }

  // fused reduce_z epilogue. C/D layout: col=lane&15, row=(lane>>4)*4+j (m89).
  // Each thread's 16 rows are monotonically increasing -> group-by-n then atomicAdd.
#pragma unroll
  for (int ni = 0; ni < 4; ++ni) {
    int col = tile_n + wn * 64 + ni * 16 + rl;
    float zac = 0.f;
    int curn = -1;
#pragma unroll
    for (int mi = 0; mi < 4; ++mi) {
#pragma unroll
      for (int j = 0; j < 4; ++j) {
        int row = tile_m + wm * 64 + mi * 16 + lh * 4 + j;
        if (row < M) {
          int n = row / L, l = row - n * L;    // L compile-time -> magic mul
          float v = acc[mi][ni][j] * w1[(size_t)col * L + l];
          if (n != curn) {
            if (curn >= 0) atomicAdd(z + curn * 1024 + col, zac);
            curn = n; zac = 0.f;
          }
          zac += v;
        }
      }
    }
    if (curn >= 0) atomicAdd(z + curn * 1024 + col, zac);
  }
}

// BN(z0), BN(z1) (biased stats over n=64), latent=0.5*(...+...), stored latT[k*64+n]
__global__ void bn_latent(const float* __restrict__ z0, const float* __restrict__ z1,
                          const float* __restrict__ g0, const float* __restrict__ b0,
                          const float* __restrict__ g1, const float* __restrict__ b1,
                          float* __restrict__ latT)
{
  int k = blockIdx.x * blockDim.x + threadIdx.x;
  if (k >= 1024) return;
  float s0 = 0.f, q0 = 0.f, s1 = 0.f, q1 = 0.f;
  for (int n = 0; n < 64; ++n) {
    float v = z0[n * 1024 + k]; s0 += v; q0 += v * v;
    float w = z1[n * 1024 + k]; s1 += w; q1 += w * w;
  }
  float mu0 = s0 * (1.f / 64.f), var0 = q0 * (1.f / 64.f) - mu0 * mu0;
  float mu1 = s1 * (1.f / 64.f), var1 = q1 * (1.f / 64.f) - mu1 * mu1;
  float sc0 = g0[k] * rsqrtf(var0 + 1e-5f);
  float sc1 = g1[k] * rsqrtf(var1 + 1e-5f);
  float be0 = b0[k], be1 = b1[k];
  for (int n = 0; n < 64; ++n) {
    float v = sc0 * (z0[n * 1024 + k] - mu0) + be0
            + sc1 * (z1[n * 1024 + k] - mu1) + be1;
    latT[k * 64 + n] = 0.5f * v;
  }
}

// s[n,p] = latT[:,n]·shared_w[p,:] + latT[:,n]·fc_w[g_n*2048+p,:] + fc_b[g_n*2048+p]
__global__ __launch_bounds__(256) void s_combine(
    const float* __restrict__ latT, const float* __restrict__ sw,
    const float* __restrict__ fw, const float* __restrict__ fb,
    const int* __restrict__ idx, float* __restrict__ s)
{
  int lane = threadIdx.x & 63;           // = n
  int wave = threadIdx.x >> 6;
  int p = blockIdx.x * 4 + wave;         // grid 512 -> p in [0,2048)
  int n = lane;
  int g = idx[n];
  const float* fwp = fw + ((size_t)g * 2048 + p) * 1024;
  const float* swp = sw + (size_t)p * 1024;
  float acc = 0.f;
#pragma unroll 4
  for (int h = 0; h < 1024; ++h) {
    float lv = latT[h * 64 + n];         // coalesced across lanes
    acc = fmaf(lv, swp[h] + fwp[h], acc);
  }
  s[n * 2048 + p] = acc + fb[(size_t)g * 2048 + p];
}

// part[by][0:64, 0:N] = s(64x2048 f32) @ embed_w^T over K-slice [by*KC, by*KC+KC)
// BM=64, BN=128, waves along N (WN=32, FN=2, FM=4). f32->bf16 staging (inputs f32).
__global__ __launch_bounds__(256) void gemm_embed(
    const float* __restrict__ A, const float* __restrict__ B, float* __restrict__ part,
    int N, int K, int KC)
{
  constexpr int BK = 32, LDT = 40;
  __shared__ short As[64 * LDT];
  __shared__ short Bs[128 * LDT];
  const int tid = threadIdx.x;
  const int lane = tid & 63;
  const int wave = tid >> 6;             // = wn, wm = 0
  const long tile_n = (long)blockIdx.x * 128;
  const int kbeg = blockIdx.y * KC;
  const int rl = lane & 15;
  const int ko = (lane >> 4) * 8;

  f32x4 acc[4][2] = {};

  for (int k0 = kbeg; k0 < kbeg + KC; k0 += BK) {
    __syncthreads();
#pragma unroll
    for (int c = 0; c < 2; ++c) {        // A: 64x32
      int f4 = c * 256 + tid;
      int r = f4 >> 3, kk = (f4 & 7) << 2;
      float4 v = *reinterpret_cast<const float4*>(A + (size_t)r * K + k0 + kk);
      short4 o; o.x = f2bf(v.x); o.y = f2bf(v.y); o.z = f2bf(v.z); o.w = f2bf(v.w);
      *reinterpret_cast<short4*>(&As[r * LDT + kk]) = o;
    }
#pragma unroll
    for (int c = 0; c < 4; ++c) {        // B: 128x32
      int f4 = c * 256 + tid;
      int r = f4 >> 3, kk = (f4 & 7) << 2;
      long gr = tile_n + r;
      float4 v = {0.f, 0.f, 0.f, 0.f};
      if (gr < N) v = *reinterpret_cast<const float4*>(B + gr * K + k0 + kk);
      short4 o; o.x = f2bf(v.x); o.y = f2bf(v.y); o.z = f2bf(v.z); o.w = f2bf(v.w);
      *reinterpret_cast<short4*>(&Bs[r * LDT + kk]) = o;
    }
    __syncthreads();

    bf16x8 af[4], bfr[2];
#pragma unroll
    for (int mi = 0; mi < 4; ++mi)
      af[mi] = *reinterpret_cast<const bf16x8*>(&As[(mi * 16 + rl) * LDT + ko]);
#pragma unroll
    for (int ni = 0; ni < 2; ++ni)
      bfr[ni] = *reinterpret_cast<const bf16x8*>(&Bs[(wave * 32 + ni * 16 + rl) * LDT + ko]);
#pragma unroll
    for (int mi = 0; mi < 4; ++mi)
#pragma unroll
      for (int ni = 0; ni < 2; ++ni)
        acc[mi][ni] = __builtin_amdgcn_mfma_f32_16x16x32_bf16(af[mi], bfr[ni], acc[mi][ni], 0, 0, 0);
  }

  float* Cp = part + (size_t)blockIdx.y * 64 * N;
#pragma unroll
  for (int ni = 0; ni < 2; ++ni) {
    long col = tile_n + wave * 32 + ni * 16 + rl;
    if (col >= N) continue;
#pragma unroll
    for (int mi = 0; mi < 4; ++mi)
#pragma unroll
      for (int j = 0; j < 4; ++j) {
        int row = mi * 16 + (lane >> 4) * 4 + j;   // < 64
        Cp[(size_t)row * N + col] = acc[mi][ni][j];
      }
  }
}

// out = part[0]+part[1]+part[2]+part[3] + 2*embed_b  (float4)
__global__ __launch_bounds__(256) void reduce_out(
    const float* __restrict__ part, const float* __restrict__ eb,
    float* __restrict__ out)
{
  const int NT = 39548;                       // divisible by 4
  const size_t S = (size_t)64 * NT / 4;       // f4 elems per split slab
  size_t i = (size_t)blockIdx.x * 256 + threadIdx.x;
  if (i >= S) return;
  const f32x4* p = reinterpret_cast<const f32x4*>(part);
  f32x4 a = p[i] + p[i + S];
  a = a + p[i + 2 * S];
  a = a + p[i + 3 * S];
  int col = (int)(i % (NT / 4)) * 4;
  f32x4 b = *reinterpret_cast<const f32x4*>(eb + col);
  f32x4 r;
  r[0] = a[0] + 2.f * b[0];
  r[1] = a[1] + 2.f * b[1];
  r[2] = a[2] + 2.f * b[2];
  r[3] = a[3] + 2.f * b[3];
  reinterpret_cast<f32x4*>(out)[i] = r;
}

extern "C" void kernel_launch(void* const* d_in, const int* in_sizes, int n_in,
                              void* d_out, int out_size, void* d_ws, size_t ws_size,
                              hipStream_t stream)
{
  const float* x0       = (const float*)d_in[0];
  const float* x1       = (const float*)d_in[1];
  const float* w1_0     = (const float*)d_in[2];
  const float* w2_0     = (const float*)d_in[3];
  const float* gamma0   = (const float*)d_in[4];
  const float* beta0    = (const float*)d_in[5];
  const float* w1_1     = (const float*)d_in[6];
  const float* w2_1     = (const float*)d_in[7];
  const float* gamma1   = (const float*)d_in[8];
  const float* beta1    = (const float*)d_in[9];
  const float* shared_w = (const float*)d_in[10];
  const float* fc_w     = (const float*)d_in[11];
  const float* fc_b     = (const float*)d_in[12];
  const float* embed_w  = (const float*)d_in[13];
  const float* embed_b  = (const float*)d_in[14];
  const int*   indices  = (const int*)d_in[15];
  float* out = (float*)d_out;

  // ws layout (bf16 region reused as embed partials later)
  short* x0b  = (short*)d_ws;                       // 16512 x 1024 (64 pad rows)
  short* x1b  = x0b + (size_t)16512 * 1024;         // 12672 x 768  (64 pad rows)
  short* w20b = x1b + (size_t)12672 * 768;          // 1024 x 1024
  short* w21b = w20b + (size_t)1024 * 1024;         // 1024 x 768
  float* z0   = (float*)(w21b + (size_t)1024 * 768);
  float* z1   = z0 + 64 * 1024;
  float* latT = z1 + 64 * 1024;
  float* s    = latT + 64 * 1024;
  float* part = (float*)d_ws;                       // 4 x 64 x 39548 f32 = 40.5MB, fits in bf16 region

  // zero z0,z1 (contiguous) for the fused-reduce atomics
  hipMemsetAsync(z0, 0, 2 * 64 * 1024 * sizeof(float), stream);

  // bf16 pre-pass
  to_bf16<<<8224, 256, 0, stream>>>(x0, x0b, 16448 * 1024 / 8);
  hipMemsetAsync(x0b + (size_t)16448 * 1024, 0, 64 * 1024 * sizeof(short), stream);
  to_bf16<<<4728, 256, 0, stream>>>(x1, x1b, 12608 * 768 / 8);
  hipMemsetAsync(x1b + (size_t)12608 * 768, 0, 64 * 768 * sizeof(short), stream);
  to_bf16<<<512, 256, 0, stream>>>(w2_0, w20b, 1024 * 1024 / 8);
  to_bf16<<<384, 256, 0, stream>>>(w2_1, w21b, 1024 * 768 / 8);

  // feature projections with fused l-reduction
  gemm_fused<257><<<dim3(8, 129), 256, 0, stream>>>(x0b, w20b, w1_0, z0, 16448, 1024);
  gemm_fused<197><<<dim3(8, 99),  256, 0, stream>>>(x1b, w21b, w1_1, z1, 12608, 768);

  // BN + latent (transposed)
  bn_latent<<<4, 256, 0, stream>>>(z0, z1, gamma0, beta0, gamma1, beta1, latT);
  // s = latent@shared_w^T + gathered fc part + fc_b
  s_combine<<<512, 256, 0, stream>>>(latT, shared_w, fc_w, fc_b, indices, s);

  // out = s @ embed_w^T + 2*embed_b, K split x4 for occupancy
  gemm_embed<<<dim3(309, 4), 256, 0, stream>>>(s, embed_w, part, 39548, 2048, 512);
  reduce_out<<<2472, 256, 0, stream>>>(part, embed_b, out);
}